// Round 16
// baseline (147.329 us; speedup 1.0000x reference)
//
#include <hip/hip_runtime.h>
#include <math.h>

typedef float f32x4 __attribute__((ext_vector_type(4)));
typedef short s16x8 __attribute__((ext_vector_type(8)));
typedef unsigned short u16;
typedef u16 u16x4 __attribute__((ext_vector_type(4)));
typedef unsigned int u32;

#define NCH 8         // J-chunks per (b,h): 8192/8 = 1024 J per block
#define NT  32        // tiles per chunk (1024/32)

__device__ __forceinline__ u16 f2bf(float f){
  union { float f; u32 u; } v; v.f = f;
  u32 r = v.u + 0x7FFFu + ((v.u >> 16) & 1u);
  return (u16)(r >> 16);
}
__device__ __forceinline__ float bf2f(u16 b){
  union { u32 u; float f; } v; v.u = ((u32)b) << 16; return v.f;
}
__device__ __forceinline__ f32x4 mfma16(s16x8 a, s16x8 b, f32x4 c){
  return __builtin_amdgcn_mfma_f32_16x16x32_bf16(a, b, c, 0, 0, 0);
}

// ---------------- k0: x fp32 -> xbf [b][j][f] and xT [b][f][j] (bf16) ----------------
__global__ __launch_bounds__(256) void k0_cvt(const float* __restrict__ x,
                                              u16* __restrict__ xbf, u16* __restrict__ xT){
  __shared__ u16 T[64*68];
  const int tid = threadIdx.x;
  const int bx = blockIdx.x;
  const int b = bx >> 9, rest = bx & 511, jt = rest >> 2, ft = rest & 3;
  const float* xp = x + (long)b*2097152 + (long)jt*16384 + ft*64;
  u16* xbp = xbf + (long)b*2097152 + (long)jt*16384 + ft*64;
  #pragma unroll
  for (int p=0;p<4;++p){
    int e = p*1024 + tid*4;
    int row = e >> 6, f = e & 63;
    float4 v = *(const float4*)(xp + (long)row*256 + f);
    u16x4 u = { f2bf(v.x), f2bf(v.y), f2bf(v.z), f2bf(v.w) };
    *(u16x4*)(xbp + (long)row*256 + f) = u;
    *(u16x4*)&T[row*68 + f] = u;
  }
  __syncthreads();
  u16* xtp = xT + (long)b*2097152 + (long)(ft*64)*8192 + (long)jt*64;
  #pragma unroll
  for (int p=0;p<4;++p){
    int e = p*1024 + tid*4;
    int fr = e >> 6, j = e & 63;
    u16x4 u = { T[j*68 + fr], T[(j+1)*68 + fr], T[(j+2)*68 + fr], T[(j+3)*68 + fr] };
    *(u16x4*)(xtp + (long)fr*8192 + j) = u;
  }
}

// ---------------- k1: Q[h][i][f] = (Wa_h @ nodes[i]) * 0.125 -> bf16 ----------------
__global__ __launch_bounds__(256) void k1_q(const float* __restrict__ nodes,
    const float* __restrict__ Wa, u16* __restrict__ Qbf){
  __shared__ float nd[64];
  const int bx = blockIdx.x;
  const int h = bx >> 7, i = bx & 127;
  const int tid = threadIdx.x;
  if (tid < 64) nd[tid] = nodes[i*64 + tid];
  __syncthreads();
  const float* wp = Wa + tid*256 + h*64;
  float acc = 0.f;
  #pragma unroll
  for (int d=0; d<64; d+=4){
    float4 wv = *(const float4*)(wp + d);
    acc += nd[d]*wv.x + nd[d+1]*wv.y + nd[d+2]*wv.z + nd[d+3]*wv.w;
  }
  Qbf[(h*128 + i)*256 + tid] = f2bf(acc * 0.125f);
}

// ---------------- k2: fused flash attention over (b, h, nodeHalf, chunk) ----------------
// R13 math verbatim; pipeline deepened:
//  - double-buffered Xs/XTs -> ONE barrier per tile (write buf^1 overlaps reads of buf)
//  - depth-2 prefetch (A/B reg sets, unroll-by-2, static indices): a tile's loads get
//    ~2 compute phases of latency cover before the ds_write consumes them
//  - flds -> __shfl broadcast (frees 256B: LDS = 79,872B x2 = 159,744 <= 160KiB)
// 512 blocks (b8 x ch8 x h4 x half2) x 256 thr (4 waves), 2 blocks/CU.
__global__ __launch_bounds__(256) void k2_attn(const u16* __restrict__ xbf,
    const u16* __restrict__ xT, const u16* __restrict__ Qbf,
    u16* __restrict__ ctxp, float* __restrict__ stats){
  __shared__ u16 Xs0[32*264], Xs1[32*264];   // [j 32][k 256] pad->264
  __shared__ u16 XT0[256*40], XT1[256*40];   // [f 256][j 32] pad->40
  __shared__ u16 Pl[64*40];                  // [node 64][j 32] pad->40 (wave-private)

  const int tid = threadIdx.x;
  const int l = tid & 63, w = tid >> 6;
  const int li = l & 15, g = l >> 4;
  const int nbL = w * 16;

  const int idx = blockIdx.x;           // XCD swizzle: 8 (h,half) blocks of same (b,ch) -> same XCD
  const int q  = idx & 63;
  const int hh = idx >> 6;
  const int h = hh & 3, half = hh >> 2;
  const int b = q >> 3, ch = q & 7;
  const int nodeG = half*64 + nbL;

  s16x8 qf[8];                           // Q B-frags: 16 nodes x 256 K
  #pragma unroll
  for (int kf=0; kf<8; ++kf)
    qf[kf] = *(const s16x8*)(Qbf + ((h*128 + nodeG + li)*256 + kf*32 + g*8));

  f32x4 cacc[16];                        // ctx acc: 16 nodes x 256 f
  #pragma unroll
  for (int ff=0;ff<16;++ff){ f32x4 z = {0.f,0.f,0.f,0.f}; cacc[ff] = z; }

  float m0 = -INFINITY, ls0 = 0.f;       // ls0 per-lane partial (reduced at end)

  const u16* xb  = xbf + (long)b*2097152 + (long)ch*262144;   // 1024 rows x 256
  const u16* xtb = xT  + (long)b*2097152 + (long)ch*1024;     // col window in [f][8192]

#define PREFETCH(PXS, PXT, JB) \
  _Pragma("unroll") \
  for (int p=0;p<4;++p){ \
    PXS[p] = *(const s16x8*)(xb + (size_t)((JB) + p*8 + (tid>>5))*256 + (tid&31)*8); \
    PXT[p] = *(const s16x8*)(xtb + (size_t)(p*64 + (tid>>2))*8192 + (JB) + (tid&3)*8); \
  }

#define STAGE_WRITE(XS, XTS, PXS, PXT) \
  _Pragma("unroll") \
  for (int p=0;p<4;++p){ \
    *(s16x8*)&XS[(p*8 + (tid>>5))*264 + (tid&31)*8] = PXS[p]; \
    *(s16x8*)&XTS[(p*64 + (tid>>2))*40 + (tid&3)*8] = PXT[p]; \
  }

#define COMPUTE(XS, XTS) { \
    f32x4 s00={0.f,0.f,0.f,0.f}, s10={0.f,0.f,0.f,0.f}; \
    _Pragma("unroll") \
    for (int kf=0; kf<8; ++kf){ \
      s16x8 ax0 = *(const s16x8*)&XS[li*264 + kf*32 + g*8]; \
      s16x8 ax1 = *(const s16x8*)&XS[(16+li)*264 + kf*32 + g*8]; \
      s00 = mfma16(ax0, qf[kf], s00); \
      s10 = mfma16(ax1, qf[kf], s10); \
    } \
    float t0 = fmaxf(fmaxf(fmaxf(s00[0],s00[1]),fmaxf(s00[2],s00[3])), \
                     fmaxf(fmaxf(s10[0],s10[1]),fmaxf(s10[2],s10[3]))); \
    t0 = fmaxf(t0, __shfl_xor(t0,16)); t0 = fmaxf(t0, __shfl_xor(t0,32)); \
    float mn0 = fmaxf(m0,t0); \
    float fac0 = __expf(m0-mn0); \
    _Pragma("unroll") \
    for (int rr=0;rr<4;++rr){ \
      s00[rr]=__expf(s00[rr]-mn0); s10[rr]=__expf(s10[rr]-mn0); \
    } \
    float u0 = s00[0]+s00[1]+s00[2]+s00[3] + s10[0]+s10[1]+s10[2]+s10[3]; \
    ls0 = ls0*fac0 + u0; \
    const bool nochange = __all(fac0==1.0f); \
    m0 = mn0; \
    { \
      u16x4 p00 = { f2bf(s00[0]),f2bf(s00[1]),f2bf(s00[2]),f2bf(s00[3]) }; \
      u16x4 p10 = { f2bf(s10[0]),f2bf(s10[1]),f2bf(s10[2]),f2bf(s10[3]) }; \
      *(u16x4*)&Pl[(nbL+li)*40 + g*4]      = p00; \
      *(u16x4*)&Pl[(nbL+li)*40 + 16 + g*4] = p10; \
    } \
    if (!nochange){ \
      float fr0[4]; \
      _Pragma("unroll") \
      for (int rr=0;rr<4;++rr){ fr0[rr] = __shfl(fac0, nbL? (g*4+rr) : (g*4+rr)); } \
      _Pragma("unroll") \
      for (int ff=0; ff<16; ++ff) \
        _Pragma("unroll") \
        for (int rr=0;rr<4;++rr){ cacc[ff][rr]*=fr0[rr]; } \
    } \
    s16x8 pa0 = *(const s16x8*)&Pl[(nbL+li)*40 + g*8]; \
    _Pragma("unroll") \
    for (int ff=0; ff<16; ++ff){ \
      s16x8 bx = *(const s16x8*)&XTS[(ff*16+li)*40 + g*8]; \
      cacc[ff] = mfma16(pa0, bx, cacc[ff]); \
    } \
  }

  s16x8 pXsA[4], pXTA[4], pXsB[4], pXTB[4];
  PREFETCH(pXsA, pXTA, 0);
  PREFETCH(pXsB, pXTB, 32);

  for (int tt=0; tt<NT; tt+=2){
    // EVEN tile tt -> buffers 0
    STAGE_WRITE(Xs0, XT0, pXsA, pXTA);
    __syncthreads();
    if (tt+2 < NT) PREFETCH(pXsA, pXTA, (tt+2)*32);
    COMPUTE(Xs0, XT0);
    // ODD tile tt+1 -> buffers 1 (no barrier needed before writing other buffer)
    STAGE_WRITE(Xs1, XT1, pXsB, pXTB);
    __syncthreads();
    if (tt+3 < NT) PREFETCH(pXsB, pXTB, (tt+3)*32);
    COMPUTE(Xs1, XT1);
  }

  // ---- epilogue: reduce deferred ls, write stats + unnormalized ctx (bf16) ----
  ls0 += __shfl_xor(ls0,16); ls0 += __shfl_xor(ls0,32);
  const int sb = ((b*4 + h)*NCH + ch)*128;
  if (g==0){
    stats[2*(sb + nodeG + li)    ] = m0;
    stats[2*(sb + nodeG + li) + 1] = ls0;
  }
  u16* cp = ctxp + (long)sb*256;
  #pragma unroll
  for (int ff=0;ff<16;++ff)
    #pragma unroll
    for (int rr=0;rr<4;++rr){
      int node = nodeG + g*4 + rr;
      int f = ff*16 + li;
      cp[(long)node*256 + f] = f2bf(cacc[ff][rr]);
    }
}

// ---------------- k3: combine chunks, project with Wv + bv, leaky, LayerNorm ----------------
__global__ __launch_bounds__(256) void k3_out(const u16* __restrict__ ctxp,
    const float* __restrict__ stats, const float* __restrict__ Wv,
    const float* __restrict__ bv, const float* __restrict__ gamma,
    const float* __restrict__ beta, float* __restrict__ out){
  __shared__ float ctxL[4*256];
  __shared__ float red[8];
  const int tid = threadIdx.x;
  const int bx = blockIdx.x;
  const int b = bx >> 7, node = bx & 127;
  #pragma unroll
  for (int h=0; h<4; ++h){
    float mc[NCH], lc[NCH];
    #pragma unroll
    for (int c=0;c<NCH;++c){
      int si = ((b*4+h)*NCH + c)*128 + node;
      mc[c] = stats[2*si]; lc[c] = stats[2*si+1];
    }
    float mm = mc[0];
    #pragma unroll
    for (int c=1;c<NCH;++c) mm = fmaxf(mm, mc[c]);
    float L = 0.f, acc = 0.f;
    #pragma unroll
    for (int c=0;c<NCH;++c){
      float wc = __expf(mc[c]-mm);
      L += wc*lc[c];
      acc += wc * bf2f(ctxp[((long)((b*4+h)*NCH + c)*128 + node)*256 + tid]);
    }
    ctxL[h*256 + tid] = acc / L;
  }
  __syncthreads();
  const int hh = tid >> 6;
  float o = bv[tid];
  const float* cx = &ctxL[hh*256];
  #pragma unroll 8
  for (int f=0; f<256; ++f) o = fmaf(cx[f], Wv[f*256 + tid], o);
  o = (o >= 0.f) ? o : 0.2f*o;
  float s1 = o, s2 = o*o;
  #pragma unroll
  for (int d=1; d<64; d<<=1){ s1 += __shfl_xor(s1,d); s2 += __shfl_xor(s2,d); }
  if ((tid&63)==0){ red[tid>>6] = s1; red[4 + (tid>>6)] = s2; }
  __syncthreads();
  float S1 = red[0]+red[1]+red[2]+red[3];
  float S2 = red[4]+red[5]+red[6]+red[7];
  float mu = S1 * (1.f/256.f);
  float var = S2 * (1.f/256.f) - mu*mu;
  float rs = rsqrtf(fmaxf(var, 0.f) + 1e-5f);
  out[(long)(b*128 + node)*256 + tid] = (o - mu)*rs*gamma[tid] + beta[tid];
}

extern "C" void kernel_launch(void* const* d_in, const int* in_sizes, int n_in,
                              void* d_out, int out_size, void* d_ws, size_t ws_size,
                              hipStream_t stream){
  const float* x     = (const float*)d_in[0];
  const float* nodes = (const float*)d_in[1];
  const float* Wa    = (const float*)d_in[2];
  const float* Wv    = (const float*)d_in[3];
  const float* bv    = (const float*)d_in[4];
  const float* gamma = (const float*)d_in[5];
  const float* beta  = (const float*)d_in[6];
  float* out = (float*)d_out;

  u16* xbf  = (u16*)d_ws;            // 8*8192*256 bf16       = 32 MiB
  u16* xT   = xbf + 16777216;        // transposed            = 32 MiB
  u16* Qbf  = xT + 16777216;         // 4*128*256 bf16        = 256 KiB
  u16* ctxp = Qbf + 131072;          // 8*4*8*128*256 bf16    = 16 MiB
  float* stats = (float*)(ctxp + 8388608); // 8*4*8*128*2 f32  = 256 KiB

  k0_cvt<<<dim3(4096), dim3(256), 0, stream>>>(x, xbf, xT);
  k1_q  <<<dim3(512),  dim3(256), 0, stream>>>(nodes, Wa, Qbf);
  k2_attn<<<dim3(512), dim3(256), 0, stream>>>(xbf, xT, Qbf, ctxp, stats);
  k3_out<<<dim3(1024), dim3(256), 0, stream>>>(ctxp, stats, Wv, bv, gamma, beta, out);
}

// Round 17
// 108.627 us; speedup vs baseline: 1.3563x; 1.3563x over previous
//
#include <hip/hip_runtime.h>
#include <math.h>

typedef float f32x4 __attribute__((ext_vector_type(4)));
typedef short s16x8 __attribute__((ext_vector_type(8)));
typedef unsigned short u16;
typedef u16 u16x4 __attribute__((ext_vector_type(4)));
typedef unsigned int u32;
typedef u32 u32x4 __attribute__((ext_vector_type(4)));

#define NCH 8         // J-chunks per (b,h): 8192/8 = 1024 J per block
#define NT  32        // tiles per chunk (1024/32)

__device__ __forceinline__ u16 f2bf(float f){
  union { float f; u32 u; } v; v.f = f;
  u32 r = v.u + 0x7FFFu + ((v.u >> 16) & 1u);
  return (u16)(r >> 16);
}
__device__ __forceinline__ float bf2f(u16 b){
  union { u32 u; float f; } v; v.u = ((u32)b) << 16; return v.f;
}
__device__ __forceinline__ f32x4 mfma16(s16x8 a, s16x8 b, f32x4 c){
  return __builtin_amdgcn_mfma_f32_16x16x32_bf16(a, b, c, 0, 0, 0);
}
__device__ __forceinline__ u32 pk_bf16(float lo, float hi){
  u32 r;
  asm("v_cvt_pk_bf16_f32 %0, %1, %2" : "=v"(r) : "v"(lo), "v"(hi));
  return r;
}

// ---------------- k0: x fp32 -> xT [b][f][j] (bf16) only (xbf dropped: k2 reads x) ----
__global__ __launch_bounds__(256) void k0_cvt(const float* __restrict__ x,
                                              u16* __restrict__ xT){
  __shared__ u16 T[64*68];
  const int tid = threadIdx.x;
  const int bx = blockIdx.x;
  const int b = bx >> 9, rest = bx & 511, jt = rest >> 2, ft = rest & 3;
  const float* xp = x + (long)b*2097152 + (long)jt*16384 + ft*64;
  #pragma unroll
  for (int p=0;p<4;++p){
    int e = p*1024 + tid*4;
    int row = e >> 6, f = e & 63;
    float4 v = *(const float4*)(xp + (long)row*256 + f);
    u16x4 u = { f2bf(v.x), f2bf(v.y), f2bf(v.z), f2bf(v.w) };
    *(u16x4*)&T[row*68 + f] = u;
  }
  __syncthreads();
  u16* xtp = xT + (long)b*2097152 + (long)(ft*64)*8192 + (long)jt*64;
  #pragma unroll
  for (int p=0;p<4;++p){
    int e = p*1024 + tid*4;
    int fr = e >> 6, j = e & 63;
    u16x4 u = { T[j*68 + fr], T[(j+1)*68 + fr], T[(j+2)*68 + fr], T[(j+3)*68 + fr] };
    *(u16x4*)(xtp + (long)fr*8192 + j) = u;
  }
}

// ---------------- k1: Q[h][i][f] = (Wa_h @ nodes[i]) * 0.125 -> bf16 ----------------
__global__ __launch_bounds__(256) void k1_q(const float* __restrict__ nodes,
    const float* __restrict__ Wa, u16* __restrict__ Qbf){
  __shared__ float nd[64];
  const int bx = blockIdx.x;
  const int h = bx >> 7, i = bx & 127;
  const int tid = threadIdx.x;
  if (tid < 64) nd[tid] = nodes[i*64 + tid];
  __syncthreads();
  const float* wp = Wa + tid*256 + h*64;
  float acc = 0.f;
  #pragma unroll
  for (int d=0; d<64; d+=4){
    float4 wv = *(const float4*)(wp + d);
    acc += nd[d]*wv.x + nd[d+1]*wv.y + nd[d+2]*wv.z + nd[d+3]*wv.w;
  }
  Qbf[(h*128 + i)*256 + tid] = f2bf(acc * 0.125f);
}

// ---------------- k2: fused flash attention over (b, h, nodeHalf, chunk) ----------------
// R13 structure (proven 80.5us, 2 blocks/CU) with two code-motion deltas:
//  - PREFETCH moved AFTER S2: R13 issued loads just before S2, so S2's mandatory
//    vmcnt(0) drain hit fresh loads with ~zero cover (~200-900cy exposed/iter).
//    Post-S2 issue -> full compute phase of cover before any drain/use.
//  - Xs staged DIRECTLY from fp32 x (float4 pairs + v_cvt_pk_bf16_f32 pack, 16
//    inst/thread/tile) -> xbf eliminated (k0 write traffic halved).
//  - flds LDS -> __shfl broadcast (fac for node n held by lane n&15).
// 512 blocks (b8 x ch8 x h4 x half2) x 256 thr (4 waves), 2 blocks/CU.
__global__ __launch_bounds__(256,2) void k2_attn(const float* __restrict__ x,
    const u16* __restrict__ xT, const u16* __restrict__ Qbf,
    u16* __restrict__ ctxp, float* __restrict__ stats){
  __shared__ u16 Xs[32*264];    // [j 32][k 256] pad->264
  __shared__ u16 XTs[256*40];   // [f 256][j 32] pad->40
  __shared__ u16 Pl[64*40];     // [node 64][j 32] pad->40 (wave-private regions)

  const int tid = threadIdx.x;
  const int l = tid & 63, w = tid >> 6;
  const int li = l & 15, g = l >> 4;
  const int nbL = w * 16;

  const int idx = blockIdx.x;           // XCD swizzle: 8 (h,half) blocks of same (b,ch) -> same XCD
  const int q  = idx & 63;
  const int hh = idx >> 6;
  const int h = hh & 3, half = hh >> 2;
  const int b = q >> 3, ch = q & 7;
  const int nodeG = half*64 + nbL;

  s16x8 qf[8];                           // Q B-frags: 16 nodes x 256 K
  #pragma unroll
  for (int kf=0; kf<8; ++kf)
    qf[kf] = *(const s16x8*)(Qbf + ((h*128 + nodeG + li)*256 + kf*32 + g*8));

  f32x4 cacc[16];                        // ctx acc: 16 nodes x 256 f
  #pragma unroll
  for (int ff=0;ff<16;++ff){ f32x4 z = {0.f,0.f,0.f,0.f}; cacc[ff] = z; }

  float m0 = -INFINITY, ls0 = 0.f;       // ls0 per-lane partial (reduced at end)

  const float* xbF = x  + (long)b*2097152 + (long)ch*262144;  // 1024 rows x 256 fp32
  const u16*   xtb = xT + (long)b*2097152 + (long)ch*1024;    // col window in [f][8192]

  // prologue: prefetch tile 0
  float4 pf[8];                          // Xs source: 8 floats per p-row
  s16x8 pXT[4];
  #pragma unroll
  for (int p=0;p<4;++p){
    const float* src = xbF + (size_t)(p*8 + (tid>>5))*256 + (tid&31)*8;
    pf[2*p]   = *(const float4*)(src);
    pf[2*p+1] = *(const float4*)(src + 4);
    pXT[p] = *(const s16x8*)(xtb + (size_t)(p*64 + (tid>>2))*8192 + (tid&3)*8);
  }

  for (int tt=0; tt<NT; ++tt){
    __syncthreads();                     // S1: prev LDS reads done; loads covered by prev compute

    // stage tile tt: convert fp32->bf16 (packed) + ds_writes
    #pragma unroll
    for (int p=0;p<4;++p){
      u32x4 vv = { pk_bf16(pf[2*p].x,   pf[2*p].y),
                   pk_bf16(pf[2*p].z,   pf[2*p].w),
                   pk_bf16(pf[2*p+1].x, pf[2*p+1].y),
                   pk_bf16(pf[2*p+1].z, pf[2*p+1].w) };
      *(u32x4*)&Xs[(p*8 + (tid>>5))*264 + (tid&31)*8] = vv;
      *(s16x8*)&XTs[(p*64 + (tid>>2))*40 + (tid&3)*8] = pXT[p];
    }

    __syncthreads();                     // S2: staged tile visible (vmcnt already quiet)

    // prefetch tile tt+1 AFTER S2: full compute phase of latency cover
    if (tt+1 < NT){
      const size_t jb = (size_t)(tt+1)*32;
      #pragma unroll
      for (int p=0;p<4;++p){
        const float* src = xbF + (jb + p*8 + (tid>>5))*256 + (tid&31)*8;
        pf[2*p]   = *(const float4*)(src);
        pf[2*p+1] = *(const float4*)(src + 4);
        pXT[p] = *(const s16x8*)(xtb + (size_t)(p*64 + (tid>>2))*8192 + jb + (tid&3)*8);
      }
    }

    // ---- QK^T: S^T[j 32][node 16]  (A = Xs rows j, B = Q regs) ----
    f32x4 s00={0.f,0.f,0.f,0.f}, s10={0.f,0.f,0.f,0.f};
    #pragma unroll
    for (int kf=0; kf<8; ++kf){
      s16x8 ax0 = *(const s16x8*)&Xs[li*264 + kf*32 + g*8];
      s16x8 ax1 = *(const s16x8*)&Xs[(16+li)*264 + kf*32 + g*8];
      s00 = mfma16(ax0, qf[kf], s00);
      s10 = mfma16(ax1, qf[kf], s10);
    }
    // lane holds: j = 16*jf + 4*g + r (rows), node = li (col)

    // ---- online softmax (per node over j); max cross-lane, sum deferred ----
    float t0 = fmaxf(fmaxf(fmaxf(s00[0],s00[1]),fmaxf(s00[2],s00[3])),
                     fmaxf(fmaxf(s10[0],s10[1]),fmaxf(s10[2],s10[3])));
    t0 = fmaxf(t0, __shfl_xor(t0,16)); t0 = fmaxf(t0, __shfl_xor(t0,32));
    float mn0 = fmaxf(m0,t0);
    float fac0 = __expf(m0-mn0);
    #pragma unroll
    for (int rr=0;rr<4;++rr){
      s00[rr]=__expf(s00[rr]-mn0); s10[rr]=__expf(s10[rr]-mn0);
    }
    float u0 = s00[0]+s00[1]+s00[2]+s00[3] + s10[0]+s10[1]+s10[2]+s10[3];
    ls0 = ls0*fac0 + u0;                 // per-lane partial; reduce in epilogue
    const bool nochange = __all(fac0==1.0f);
    m0 = mn0;

    // ---- P -> Pl (wave-private region) ----
    {
      u16x4 p00 = { f2bf(s00[0]),f2bf(s00[1]),f2bf(s00[2]),f2bf(s00[3]) };
      u16x4 p10 = { f2bf(s10[0]),f2bf(s10[1]),f2bf(s10[2]),f2bf(s10[3]) };
      *(u16x4*)&Pl[(nbL+li)*40 + g*4]      = p00;
      *(u16x4*)&Pl[(nbL+li)*40 + 16 + g*4] = p10;
    }

    // ---- rescale ctx (skipped once running max stabilizes); fac via shuffle ----
    if (!nochange){
      float fr0[4];
      #pragma unroll
      for (int rr=0;rr<4;++rr){ fr0[rr] = __shfl(fac0, g*4 + rr); }
      #pragma unroll
      for (int ff=0; ff<16; ++ff)
        #pragma unroll
        for (int rr=0;rr<4;++rr){ cacc[ff][rr]*=fr0[rr]; }
    }

    // ---- PV: ctx[node][f] += P * X  (A = Pl, B = XTs) ----
    s16x8 pa0 = *(const s16x8*)&Pl[(nbL+li)*40 + g*8];
    #pragma unroll
    for (int ff=0; ff<16; ++ff){
      s16x8 bx = *(const s16x8*)&XTs[(ff*16+li)*40 + g*8];
      cacc[ff] = mfma16(pa0, bx, cacc[ff]);
    }
  }

  // ---- epilogue: reduce deferred ls, write stats + unnormalized ctx (bf16) ----
  ls0 += __shfl_xor(ls0,16); ls0 += __shfl_xor(ls0,32);
  const int sb = ((b*4 + h)*NCH + ch)*128;
  if (g==0){
    stats[2*(sb + nodeG + li)    ] = m0;
    stats[2*(sb + nodeG + li) + 1] = ls0;
  }
  u16* cp = ctxp + (long)sb*256;
  #pragma unroll
  for (int ff=0;ff<16;++ff)
    #pragma unroll
    for (int rr=0;rr<4;++rr){
      int node = nodeG + g*4 + rr;
      int f = ff*16 + li;
      cp[(long)node*256 + f] = f2bf(cacc[ff][rr]);
    }
}

// ---------------- k3: combine chunks, project with Wv + bv, leaky, LayerNorm ----------------
__global__ __launch_bounds__(256) void k3_out(const u16* __restrict__ ctxp,
    const float* __restrict__ stats, const float* __restrict__ Wv,
    const float* __restrict__ bv, const float* __restrict__ gamma,
    const float* __restrict__ beta, float* __restrict__ out){
  __shared__ float ctxL[4*256];
  __shared__ float red[8];
  const int tid = threadIdx.x;
  const int bx = blockIdx.x;
  const int b = bx >> 7, node = bx & 127;
  #pragma unroll
  for (int h=0; h<4; ++h){
    float mc[NCH], lc[NCH];
    #pragma unroll
    for (int c=0;c<NCH;++c){
      int si = ((b*4+h)*NCH + c)*128 + node;
      mc[c] = stats[2*si]; lc[c] = stats[2*si+1];
    }
    float mm = mc[0];
    #pragma unroll
    for (int c=1;c<NCH;++c) mm = fmaxf(mm, mc[c]);
    float L = 0.f, acc = 0.f;
    #pragma unroll
    for (int c=0;c<NCH;++c){
      float wc = __expf(mc[c]-mm);
      L += wc*lc[c];
      acc += wc * bf2f(ctxp[((long)((b*4+h)*NCH + c)*128 + node)*256 + tid]);
    }
    ctxL[h*256 + tid] = acc / L;
  }
  __syncthreads();
  const int hh = tid >> 6;
  float o = bv[tid];
  const float* cx = &ctxL[hh*256];
  #pragma unroll 8
  for (int f=0; f<256; ++f) o = fmaf(cx[f], Wv[f*256 + tid], o);
  o = (o >= 0.f) ? o : 0.2f*o;
  float s1 = o, s2 = o*o;
  #pragma unroll
  for (int d=1; d<64; d<<=1){ s1 += __shfl_xor(s1,d); s2 += __shfl_xor(s2,d); }
  if ((tid&63)==0){ red[tid>>6] = s1; red[4 + (tid>>6)] = s2; }
  __syncthreads();
  float S1 = red[0]+red[1]+red[2]+red[3];
  float S2 = red[4]+red[5]+red[6]+red[7];
  float mu = S1 * (1.f/256.f);
  float var = S2 * (1.f/256.f) - mu*mu;
  float rs = rsqrtf(fmaxf(var, 0.f) + 1e-5f);
  out[(long)(b*128 + node)*256 + tid] = (o - mu)*rs*gamma[tid] + beta[tid];
}

extern "C" void kernel_launch(void* const* d_in, const int* in_sizes, int n_in,
                              void* d_out, int out_size, void* d_ws, size_t ws_size,
                              hipStream_t stream){
  const float* x     = (const float*)d_in[0];
  const float* nodes = (const float*)d_in[1];
  const float* Wa    = (const float*)d_in[2];
  const float* Wv    = (const float*)d_in[3];
  const float* bv    = (const float*)d_in[4];
  const float* gamma = (const float*)d_in[5];
  const float* beta  = (const float*)d_in[6];
  float* out = (float*)d_out;

  u16* xT   = (u16*)d_ws;            // 8*8192*256 bf16       = 32 MiB
  u16* Qbf  = xT + 16777216;         // 4*128*256 bf16        = 256 KiB
  u16* ctxp = Qbf + 131072;          // 8*4*8*128*256 bf16    = 16 MiB
  float* stats = (float*)(ctxp + 8388608); // 8*4*8*128*2 f32  = 256 KiB

  k0_cvt<<<dim3(4096), dim3(256), 0, stream>>>(x, xT);
  k1_q  <<<dim3(512),  dim3(256), 0, stream>>>(nodes, Wa, Qbf);
  k2_attn<<<dim3(512), dim3(256), 0, stream>>>(x, xT, Qbf, ctxp, stats);
  k3_out<<<dim3(1024), dim3(256), 0, stream>>>(ctxp, stats, Wv, bv, gamma, beta, out);
}